// Round 11
// baseline (1237.724 us; speedup 1.0000x reference)
//
#include <hip/hip_runtime.h>

#define B_   16
#define N_   4096
#define CIN  64
#define COUT 128
#define NPT  1024
#define KNNK 16

typedef unsigned long long u64;
typedef unsigned u32x2 __attribute__((ext_vector_type(2)));

__device__ __forceinline__ float fINF() { return __int_as_float(0x7f800000); }

// DPP cross-lane (VALU speed): xor1=0xB1, xor2=0x4E, rev8=0x141, rev16=0x140
template<int CTRL>
__device__ __forceinline__ float fmax_dpp(float v) {
    int x = __builtin_amdgcn_update_dpp(0, __float_as_int(v), CTRL, 0xF, 0xF, true);
    return fmaxf(v, __int_as_float(x));
}
template<int CTRL>
__device__ __forceinline__ float fmin_dpp(float v) {
    int x = __builtin_amdgcn_update_dpp(0, __float_as_int(v), CTRL, 0xF, 0xF, true);
    return fminf(v, __int_as_float(x));
}

// gfx950 VALU half-swaps (replace DS-pipe shfl_xor 16/32). Guarded so a
// missing builtin degrades to the measured R5 shfl path instead of a
// compile failure (this source has never compiled on-container yet).
#if defined(__has_builtin) && __has_builtin(__builtin_amdgcn_permlane16_swap)
__device__ __forceinline__ float fmax_p16(float v) {
    u32x2 r = __builtin_amdgcn_permlane16_swap(__float_as_uint(v), __float_as_uint(v), false, false);
    return fmaxf(__uint_as_float(r[0]), __uint_as_float(r[1]));
}
__device__ __forceinline__ float fmin_p16(float v) {
    u32x2 r = __builtin_amdgcn_permlane16_swap(__float_as_uint(v), __float_as_uint(v), false, false);
    return fminf(__uint_as_float(r[0]), __uint_as_float(r[1]));
}
#else
__device__ __forceinline__ float fmax_p16(float v) { return fmaxf(v, __shfl_xor(v, 16)); }
__device__ __forceinline__ float fmin_p16(float v) { return fminf(v, __shfl_xor(v, 16)); }
#endif
#if defined(__has_builtin) && __has_builtin(__builtin_amdgcn_permlane32_swap)
__device__ __forceinline__ float fmax_p32(float v) {
    u32x2 r = __builtin_amdgcn_permlane32_swap(__float_as_uint(v), __float_as_uint(v), false, false);
    return fmaxf(__uint_as_float(r[0]), __uint_as_float(r[1]));
}
__device__ __forceinline__ float fmin_p32(float v) {
    u32x2 r = __builtin_amdgcn_permlane32_swap(__float_as_uint(v), __float_as_uint(v), false, false);
    return fminf(__uint_as_float(r[0]), __uint_as_float(r[1]));
}
#else
__device__ __forceinline__ float fmax_p32(float v) { return fmaxf(v, __shfl_xor(v, 32)); }
__device__ __forceinline__ float fmin_p32(float v) { return fminf(v, __shfl_xor(v, 32)); }
#endif

__device__ __forceinline__ float readlane_f(float v, int l) {
    return __int_as_float(__builtin_amdgcn_readlane(__float_as_int(v), l));
}

// ---------------------------------------------------------------------------
// K1: FPS. 512 thr/batch, 8 pts/thread. One barrier/step. Wave reduce is
// VALU-only (4 DPP + permlane16_swap + permlane32_swap); winner lane writes
// {val,x,y,z}+idx slot; post-barrier: parallel b128+b32 slot reads, 3-DPP
// combine, ballot, 4 readlanes (scalar broadcast). Tie order: lowest slot
// (=wave) -> lowest lane -> lowest j == lowest index == jnp.argmax.
// ---------------------------------------------------------------------------
__global__ __launch_bounds__(512) void fps_kernel(const float* __restrict__ p,
                                                  int* __restrict__ idx_out,
                                                  float* __restrict__ newp_out) {
    __shared__ float  sx[N_], sy[N_], sz[N_];
    __shared__ int    sidx[NPT];
    __shared__ float4 scoord[2][8];   // {val, x, y, z}
    __shared__ int    swidx[2][8];

    const int b = blockIdx.x;
    const int t = threadIdx.x;
    const int lane = t & 63;
    const int wave = t >> 6;
    const float* pb = p + (size_t)b * N_ * 3;

    // coalesced SoA staging (coord lookup for final output)
    for (int i = 0; i < 24; ++i) {
        int f = t + 512 * i;
        float v = pb[f];
        int pt = f / 3, c = f - pt * 3;
        if (c == 0) sx[pt] = v; else if (c == 1) sy[pt] = v; else sz[pt] = v;
    }

    // register copy of own 8 points: float4 [6t, 6t+6)
    const float4* pb4 = (const float4*)pb;
    float4 a0 = pb4[6*t+0], a1 = pb4[6*t+1], a2 = pb4[6*t+2];
    float4 a3 = pb4[6*t+3], a4 = pb4[6*t+4], a5 = pb4[6*t+5];
    float lx[8], ly[8], lz[8], dist[8];
    lx[0]=a0.x; ly[0]=a0.y; lz[0]=a0.z;
    lx[1]=a0.w; ly[1]=a1.x; lz[1]=a1.y;
    lx[2]=a1.z; ly[2]=a1.w; lz[2]=a2.x;
    lx[3]=a2.y; ly[3]=a2.z; lz[3]=a2.w;
    lx[4]=a3.x; ly[4]=a3.y; lz[4]=a3.z;
    lx[5]=a3.w; ly[5]=a4.x; lz[5]=a4.y;
    lx[6]=a4.z; ly[6]=a4.w; lz[6]=a5.x;
    lx[7]=a5.y; ly[7]=a5.z; lz[7]=a5.w;
#pragma unroll
    for (int j = 0; j < 8; ++j) dist[j] = 1e10f;

    float cx = pb[0], cy = pb[1], cz = pb[2];   // far = 0
    if (t == 0) sidx[0] = 0;
    // no pre-loop barrier needed: step-1 barrier orders staging writes
    // before the first post-barrier sx/sy/sz reads (final output loop).

    for (int s = 1; s < NPT; ++s) {
        const int par = s & 1;
        // ---- phase A: update (arithmetic identical to passed rounds) ----
        float nd[8];
#pragma unroll
        for (int j = 0; j < 8; ++j) {
            float dx = lx[j]-cx, dy = ly[j]-cy, dz = lz[j]-cz;
            float d = dx*dx + dy*dy + dz*dz;
            nd[j] = fminf(dist[j], d);
            dist[j] = nd[j];
        }
        float lmax = fmaxf(fmaxf(fmaxf(nd[0],nd[1]), fmaxf(nd[2],nd[3])),
                           fmaxf(fmaxf(nd[4],nd[5]), fmaxf(nd[6],nd[7])));
        float bv = lmax;
        bv = fmax_dpp<0xB1>(bv);
        bv = fmax_dpp<0x4E>(bv);
        bv = fmax_dpp<0x141>(bv);
        bv = fmax_dpp<0x140>(bv);
        bv = fmax_p16(bv);
        bv = fmax_p32(bv);
        u64 ball = __ballot(lmax == bv);
        int winlane = (int)__builtin_ctzll(ball);
        if (lane == winlane) {
            int cj = 7;
#pragma unroll
            for (int jj = 7; jj >= 0; --jj)
                if (nd[jj] == bv) cj = jj;           // lowest matching j
            float wx = lx[0], wy = ly[0], wz = lz[0];
#pragma unroll
            for (int jj = 1; jj < 8; ++jj)
                if (cj == jj) { wx = lx[jj]; wy = ly[jj]; wz = lz[jj]; }
            float4 r; r.x = bv; r.y = wx; r.z = wy; r.w = wz;
            scoord[par][wave] = r;
            swidx[par][wave] = t * 8 + cj;
        }
        __syncthreads();
        // ---- phase B: combine 8 slots, broadcast via readlane ----
        float4 c4 = scoord[par][lane & 7];
        int    ix = swidx[par][lane & 7];
        float gv = c4.x;
        gv = fmax_dpp<0xB1>(gv);
        gv = fmax_dpp<0x4E>(gv);
        gv = fmax_dpp<0x141>(gv);
        u64 b2 = __ballot(c4.x == gv);
        int winslot = (int)__builtin_ctzll(b2);      // lowest lane = lowest slot
        cx = readlane_f(c4.y, winslot);
        cy = readlane_f(c4.z, winslot);
        cz = readlane_f(c4.w, winslot);
        int widx = __builtin_amdgcn_readlane(ix, winslot);
        if (t == 0) sidx[s] = widx;
    }
    __syncthreads();

    for (int s2 = t; s2 < NPT; s2 += 512) {
        int i = sidx[s2];
        idx_out[b * NPT + s2] = i;
        float* np = newp_out + ((size_t)b * NPT + s2) * 3;
        np[0] = sx[i]; np[1] = sy[i]; np[2] = sz[i];
    }
}

// ---------------------------------------------------------------------------
// K2: KNN. 256 thr/query, 16 pts/thread, 17 extraction rounds, 1 barrier
// each. Reduce VALU-only (DPP + permlane swaps); widx broadcast via
// readlane. Removal/rescan wave-uniformly guarded. Ties = lax.top_k.
// ---------------------------------------------------------------------------
__global__ __launch_bounds__(256) void knn_kernel(const float* __restrict__ p,
                                                  const int* __restrict__ idx_in,
                                                  int* __restrict__ knn_out) {
    __shared__ u64 skey[2][4];

    const int blk = blockIdx.x;
    const int b = blk >> 10, n = blk & 1023;
    const int t = threadIdx.x;
    const int lane = t & 63, wave = t >> 6;
    const float* pb = p + (size_t)b * N_ * 3;

    const int qi = idx_in[b * NPT + n];
    const float qx = pb[qi * 3 + 0], qy = pb[qi * 3 + 1], qz = pb[qi * 3 + 2];

    float fl[48];
    const float4* pb4 = (const float4*)pb;
#pragma unroll
    for (int i = 0; i < 12; ++i) {
        float4 v = pb4[t * 12 + i];
        fl[4 * i + 0] = v.x; fl[4 * i + 1] = v.y; fl[4 * i + 2] = v.z; fl[4 * i + 3] = v.w;
    }
    float dist[16];
#pragma unroll
    for (int j = 0; j < 16; ++j) {
        float dx = fl[3 * j + 0] - qx;
        float dy = fl[3 * j + 1] - qy;
        float dz = fl[3 * j + 2] - qz;
        dist[j] = dx * dx + dy * dy + dz * dz;
    }

    float lmin;
    {
        float m0 = fminf(fminf(dist[0], dist[1]), fminf(dist[2], dist[3]));
        float m1 = fminf(fminf(dist[4], dist[5]), fminf(dist[6], dist[7]));
        float m2 = fminf(fminf(dist[8], dist[9]), fminf(dist[10], dist[11]));
        float m3 = fminf(fminf(dist[12], dist[13]), fminf(dist[14], dist[15]));
        lmin = fminf(fminf(m0, m1), fminf(m2, m3));
    }

    int* kout = knn_out + ((size_t)b * NPT + n) * KNNK;

    for (int r = 0; r < 17; ++r) {
        const int par = r & 1;
        float wv = lmin;
        wv = fmin_dpp<0xB1>(wv);
        wv = fmin_dpp<0x4E>(wv);
        wv = fmin_dpp<0x141>(wv);
        wv = fmin_dpp<0x140>(wv);
        wv = fmin_p16(wv);
        wv = fmin_p32(wv);
        u64 ball = __ballot(lmin == wv);
        int winlane = (int)__builtin_ctzll(ball);
        if (lane == winlane) {
            int j = 15;
#pragma unroll
            for (int jj = 15; jj >= 0; --jj)
                if (dist[jj] == wv) j = jj;          // lowest matching j
            skey[par][wave] = ((u64)__float_as_uint(wv) << 32) | (unsigned)(t * 16 + j);
        }
        __syncthreads();
        u64 k = skey[par][lane & 3];
        float v = __uint_as_float((unsigned)(k >> 32));
        float gmin = v;
        gmin = fmin_dpp<0xB1>(gmin);
        gmin = fmin_dpp<0x4E>(gmin);
        u64 b2 = __ballot(v == gmin);
        int winslot = (int)__builtin_ctzll(b2);      // lowest lane = lowest slot
        const int widx = __builtin_amdgcn_readlane((int)(unsigned)(k & 0xFFFFFFFFull), winslot);
        if (t == 0 && r > 0) kout[r - 1] = widx;
        if ((widx >> 10) == wave) {                  // wave-uniform guard
            if ((widx >> 4) == t) {
#pragma unroll
                for (int jj = 0; jj < 16; ++jj)
                    if ((widx & 15) == jj) dist[jj] = fINF();
                float m0 = fminf(fminf(dist[0], dist[1]), fminf(dist[2], dist[3]));
                float m1 = fminf(fminf(dist[4], dist[5]), fminf(dist[6], dist[7]));
                float m2 = fminf(fminf(dist[8], dist[9]), fminf(dist[10], dist[11]));
                float m3 = fminf(fminf(dist[12], dist[13]), fminf(dist[14], dist[15]));
                lmin = fminf(fminf(m0, m1), fminf(m2, m3));
            }
        }
    }
}

// ---------------------------------------------------------------------------
// K3: second-moment stats (unchanged)
// ---------------------------------------------------------------------------
__global__ __launch_bounds__(256) void stats_kernel(const float* __restrict__ x,
                                                    const int* __restrict__ idx_in,
                                                    const int* __restrict__ knn_in,
                                                    float* __restrict__ part) {
    __shared__ float xc[4 * 64];
    __shared__ float dls[64 * 72];

    const int blk = blockIdx.x;
    const int t = threadIdx.x;
    const int q0 = blk * 64;
    const int b = q0 >> 10;
    const float* xb = x + (size_t)b * N_ * CIN;

    float acc[4][4];
#pragma unroll
    for (int i = 0; i < 4; ++i)
#pragma unroll
        for (int j = 0; j < 4; ++j) acc[i][j] = 0.f;
    float dsum = 0.f;

    const int r0 = (t >> 4) * 4, c0 = (t & 15) * 4;

    for (int sg = 0; sg < 16; ++sg) {
        __syncthreads();
        {
            int qq = t >> 6, c = t & 63;
            int q = q0 + sg * 4 + qq;
            int ci = idx_in[q];
            xc[qq * 64 + c] = xb[ci * CIN + c];
        }
        __syncthreads();
        for (int i = 0; i < 16; ++i) {
            int f = t + 256 * i;
            int qq = f >> 10, k = (f >> 6) & 15, c = f & 63;
            int q = q0 + sg * 4 + qq;
            int row = knn_in[q * KNNK + k];
            dls[(qq * 16 + k) * 72 + c] = xc[qq * 64 + c] - xb[row * CIN + c];
        }
        __syncthreads();
#pragma unroll 4
        for (int s = 0; s < 64; ++s) {
            const float4 a  = *(const float4*)&dls[s * 72 + r0];
            const float4 bb = *(const float4*)&dls[s * 72 + c0];
            acc[0][0] += a.x * bb.x; acc[0][1] += a.x * bb.y; acc[0][2] += a.x * bb.z; acc[0][3] += a.x * bb.w;
            acc[1][0] += a.y * bb.x; acc[1][1] += a.y * bb.y; acc[1][2] += a.y * bb.z; acc[1][3] += a.y * bb.w;
            acc[2][0] += a.z * bb.x; acc[2][1] += a.z * bb.y; acc[2][2] += a.z * bb.z; acc[2][3] += a.z * bb.w;
            acc[3][0] += a.w * bb.x; acc[3][1] += a.w * bb.y; acc[3][2] += a.w * bb.z; acc[3][3] += a.w * bb.w;
        }
        if (t < 64) {
            for (int s = 0; s < 64; ++s) dsum += dls[s * 72 + t];
        }
    }

    float* pout = part + (size_t)blk * 4160;
#pragma unroll
    for (int i = 0; i < 4; ++i)
#pragma unroll
        for (int j = 0; j < 4; ++j)
            pout[(r0 + i) * 64 + (c0 + j)] = acc[i][j];
    if (t < 64) pout[4096 + t] = dsum;
}

__global__ __launch_bounds__(256) void reduce_kernel(const float* __restrict__ part,
                                                     float* __restrict__ M) {
    int e = blockIdx.x * 256 + threadIdx.x;
    if (e >= 4160) return;
    float s = 0.f;
    for (int b = 0; b < 256; ++b) s += part[(size_t)b * 4160 + e];
    M[e] = s;
}

__global__ __launch_bounds__(64) void scale_kernel(const float* __restrict__ M,
                                                   const float* __restrict__ w,
                                                   const float* __restrict__ gamma,
                                                   const float* __restrict__ beta,
                                                   float* __restrict__ st) {
    __shared__ float wv[64];
    const int o = blockIdx.x, t = threadIdx.x;
    wv[t] = w[o * 64 + t];
    __syncthreads();
    const float* Mr = M + t * 64;
    float sr = 0.f;
    for (int c = 0; c < 64; ++c) sr += Mr[c] * wv[c];
    float e2 = wv[t] * sr;
    float mn = wv[t] * M[4096 + t];
#pragma unroll
    for (int off = 32; off >= 1; off >>= 1) {
        e2 += __shfl_xor(e2, off);
        mn += __shfl_xor(mn, off);
    }
    if (t == 0) {
        const float Ns = 262144.0f;
        float mean = mn / Ns;
        float var = e2 / Ns - mean * mean;
        float scale = gamma[o] * rsqrtf(var + 1e-5f);
        st[o] = scale;
        st[128 + o] = beta[o] - mean * scale;
    }
}

// ---------------------------------------------------------------------------
// K5: fused output (unchanged)
// ---------------------------------------------------------------------------
__global__ __launch_bounds__(256) void out_kernel(const float* __restrict__ x,
                                                  const float* __restrict__ w,
                                                  const int* __restrict__ idx_in,
                                                  const int* __restrict__ knn_in,
                                                  const float* __restrict__ st,
                                                  float* __restrict__ out) {
    __shared__ float wT[64 * 132];        // wT[c][o]
    __shared__ float ss[256];
    __shared__ float df4[16 * 260];       // df4[k*260 + c*4 + q]
    __shared__ int   skr[64];
    __shared__ int   sci[4];

    const int blk = blockIdx.x;           // 4096 blocks
    const int b = blk >> 8, n0 = (blk & 255) * 4;
    const int t = threadIdx.x;
    const float* xb = x + (size_t)b * N_ * CIN;

    for (int i = 0; i < 32; ++i) {
        int f = t + 256 * i;
        int o = f >> 6, c = f & 63;
        wT[c * 132 + o] = w[f];
    }
    ss[t] = st[t];
    if (t < 64) skr[t] = knn_in[((size_t)b * NPT + n0) * KNNK + t];
    if (t < 4)  sci[t] = idx_in[b * NPT + n0 + t];
    __syncthreads();

    for (int i = 0; i < 16; ++i) {
        int c = t >> 2, q = t & 3;
        int center = sci[q];
        int row = skr[q * 16 + i];
        df4[i * 260 + c * 4 + q] = xb[center * CIN + c] - xb[row * CIN + c];
    }
    __syncthreads();

    const int k = t & 15, oq = t >> 4;
    float acc[4][8];
#pragma unroll
    for (int q = 0; q < 4; ++q)
#pragma unroll
        for (int i = 0; i < 8; ++i) acc[q][i] = 0.f;

    const float* dr = &df4[k * 260];
    for (int c = 0; c < 64; ++c) {
        const float4 d4 = *(const float4*)&dr[c * 4];
        const float4 w0 = *(const float4*)&wT[c * 132 + oq * 8 + 0];
        const float4 w1 = *(const float4*)&wT[c * 132 + oq * 8 + 4];
        float dv[4] = {d4.x, d4.y, d4.z, d4.w};
        float wvv[8] = {w0.x, w0.y, w0.z, w0.w, w1.x, w1.y, w1.z, w1.w};
#pragma unroll
        for (int q = 0; q < 4; ++q)
#pragma unroll
            for (int i = 0; i < 8; ++i) acc[q][i] += dv[q] * wvv[i];
    }

#pragma unroll
    for (int q = 0; q < 4; ++q)
#pragma unroll
        for (int i = 0; i < 8; ++i) {
            int o = oq * 8 + i;
            float v = fmaxf(acc[q][i] * ss[o] + ss[128 + o], 0.f);
            v = fmax_dpp<0xB1>(v);
            v = fmax_dpp<0x4E>(v);
            v = fmax_dpp<0x141>(v);
            v = fmax_dpp<0x140>(v);
            acc[q][i] = v;
        }
    if (k == 0) {
#pragma unroll
        for (int q = 0; q < 4; ++q) {
            float4 o0 = {acc[q][0], acc[q][1], acc[q][2], acc[q][3]};
            float4 o1 = {acc[q][4], acc[q][5], acc[q][6], acc[q][7]};
            float* op = out + ((size_t)b * NPT + n0 + q) * COUT + oq * 8;
            *(float4*)&op[0] = o0;
            *(float4*)&op[4] = o1;
        }
    }
}

// ---------------------------------------------------------------------------
extern "C" void kernel_launch(void* const* d_in, const int* in_sizes, int n_in,
                              void* d_out, int out_size, void* d_ws, size_t ws_size,
                              hipStream_t stream) {
    const float* x     = (const float*)d_in[0];
    const float* p     = (const float*)d_in[1];
    const float* w     = (const float*)d_in[2];
    const float* gamma = (const float*)d_in[3];
    const float* beta  = (const float*)d_in[4];

    float* out  = (float*)d_out;                               // [16,1024,128]
    float* newp = out + (size_t)B_ * NPT * COUT;               // [16,1024,3]

    char* ws = (char*)d_ws;
    int*   idx  = (int*)(ws + 0);           // 16384 ints
    int*   knn  = (int*)(ws + 65536);       // 262144 ints
    float* part = (float*)(ws + 1114112);   // 256*4160 floats
    float* M    = (float*)(ws + 5373952);   // 4160 floats
    float* st   = (float*)(ws + 5390592);   // 256 floats

    hipLaunchKernelGGL(fps_kernel,   dim3(B_),          dim3(512),  0, stream, p, idx, newp);
    hipLaunchKernelGGL(knn_kernel,   dim3(B_ * NPT),    dim3(256),  0, stream, p, idx, knn);
    hipLaunchKernelGGL(stats_kernel, dim3(256),         dim3(256),  0, stream, x, idx, knn, part);
    hipLaunchKernelGGL(reduce_kernel,dim3(17),          dim3(256),  0, stream, part, M);
    hipLaunchKernelGGL(scale_kernel, dim3(128),         dim3(64),   0, stream, M, w, gamma, beta, st);
    hipLaunchKernelGGL(out_kernel,   dim3(B_ * NPT/4),  dim3(256),  0, stream, x, w, idx, knn, st, out);
}